// Round 2
// baseline (5219.217 us; speedup 1.0000x reference)
//
#include <hip/hip_runtime.h>
#include <hip/hip_bf16.h>
#include <math.h>

#define SEQ 2048
#define DIM 4096
#define NH 32
#define HD 128
#define NKV 8
#define NREP 4
#define BLOCK 64
#define NBLK 32
#define TOPK 8
#define KVDIM (NKV * HD)   // 1024
#define SCALE 0.08838834764831845f
#define NEGV (-1e30f)

// ---------------- Tiled GEMM: C(MxN) = A(MxK) @ B(KxN), fp32 accumulate ----------------
// BM=BN=64, BK=16, 256 threads, 4x4 per thread. All fp32.
__global__ __launch_bounds__(256) void gemm_kernel(const float* __restrict__ A,
                                                   const float* __restrict__ B,
                                                   float* __restrict__ C,
                                                   int M, int N, int K) {
    __shared__ __align__(16) float As[16][68];  // [k][m], padded row (272B, 16B-aligned)
    __shared__ __align__(16) float Bs[16][68];  // [k][n]

    const int tid = threadIdx.x;
    const int bm = blockIdx.y * 64;
    const int bn = blockIdx.x * 64;
    const int tm = (tid >> 4) * 4;   // row offset in tile
    const int tn = (tid & 15) * 4;   // col offset in tile

    float acc[4][4] = {};

    for (int k0 = 0; k0 < K; k0 += 16) {
        // Load A tile: 64 rows x 16 k. thread t -> row t>>2, k-chunk (t&3)*4
        {
            const int m = tid >> 2;
            const int kk = (tid & 3) * 4;
            const float* ap = A + (size_t)(bm + m) * K + k0 + kk;
            const float4 a4 = *reinterpret_cast<const float4*>(ap);
            As[kk + 0][m] = a4.x;
            As[kk + 1][m] = a4.y;
            As[kk + 2][m] = a4.z;
            As[kk + 3][m] = a4.w;
        }
        // Load B tile: 16 k rows x 64 n. thread t -> k row t>>4, n-chunk (t&15)*4
        {
            const int kk = tid >> 4;
            const int n = (tid & 15) * 4;
            const float* bp = B + (size_t)(k0 + kk) * N + bn + n;
            *reinterpret_cast<float4*>(&Bs[kk][n]) = *reinterpret_cast<const float4*>(bp);
        }
        __syncthreads();
#pragma unroll
        for (int kk = 0; kk < 16; ++kk) {
            const float4 a4 = *reinterpret_cast<const float4*>(&As[kk][tm]);
            const float4 b4 = *reinterpret_cast<const float4*>(&Bs[kk][tn]);
            const float av[4] = {a4.x, a4.y, a4.z, a4.w};
            const float bv[4] = {b4.x, b4.y, b4.z, b4.w};
#pragma unroll
            for (int i = 0; i < 4; ++i)
#pragma unroll
                for (int j = 0; j < 4; ++j) acc[i][j] += av[i] * bv[j];
        }
        __syncthreads();
    }
#pragma unroll
    for (int i = 0; i < 4; ++i)
#pragma unroll
        for (int j = 0; j < 4; ++j)
            C[(size_t)(bm + tm + i) * N + bn + tn + j] = acc[i][j];
}

// ---------------- RoPE (in place, fp32 buffer). Pairs are adjacent (2i, 2i+1). -------
__global__ void rope_kernel(float* __restrict__ x, const float* __restrict__ cosb,
                            const float* __restrict__ sinb, int nh) {
    const int idx = blockIdx.x * blockDim.x + threadIdx.x;  // pair index
    const int i = idx & 63;            // freq index (HD/2 = 64)
    const int h = (idx >> 6) % nh;
    const int pos = idx / (64 * nh);
    const float c = cosb[pos * 64 + i];
    const float s = sinb[pos * 64 + i];
    float* p = x + ((size_t)pos * nh + h) * HD + 2 * i;
    const float x0 = p[0], x1 = p[1];
    p[0] = x0 * c - x1 * s;
    p[1] = x0 * s + x1 * c;
}

// ---------------- Block means of K: kblk[kv][blk][d] ----------------
__global__ void blkmean_kernel(const float* __restrict__ k, float* __restrict__ kblk) {
    const int idx = blockIdx.x * blockDim.x + threadIdx.x;  // 8*32*128 = 32768
    const int d = idx & 127;
    const int blk = (idx >> 7) & 31;
    const int kv = idx >> 12;
    float s = 0.f;
#pragma unroll 8
    for (int r = 0; r < BLOCK; ++r)
        s += k[(size_t)(blk * BLOCK + r) * KVDIM + kv * HD + d];
    kblk[idx] = s * (1.f / 64.f);
}

// ---------------- Sparse attention: one wave (64 threads) per (pos, head) -----------
__global__ __launch_bounds__(64) void attn_kernel(const float* __restrict__ q,
                                                  const float* __restrict__ k,
                                                  const float* __restrict__ v,
                                                  const float* __restrict__ kblk,
                                                  float* __restrict__ attn_out) {
    const int pos = blockIdx.x;
    const int h = blockIdx.y;
    const int kv = h >> 2;  // h / NREP
    const int lane = threadIdx.x;

    __shared__ float sc[TOPK * BLOCK];  // 512 probabilities

    const float* qp = q + ((size_t)pos * NH + h) * HD;

    // ---- block scores (lanes 0..31); disallowed and lanes>=32 get NEG ----
    float val = NEGV;
    if (lane < NBLK && lane * BLOCK <= pos) {
        const float* kb = kblk + ((size_t)kv * NBLK + lane) * HD;
        float s = 0.f;
#pragma unroll
        for (int d = 0; d < HD; d += 4) {
            const float4 qv = *reinterpret_cast<const float4*>(qp + d);
            const float4 kb4 = *reinterpret_cast<const float4*>(kb + d);
            s += qv.x * kb4.x + qv.y * kb4.y + qv.z * kb4.z + qv.w * kb4.w;
        }
        val = s * SCALE;
    }

    // ---- top-8 argmax, ties -> lower index (matches jax.lax.top_k) ----
    const int myidx = lane;
    int sel[TOPK];
#pragma unroll
    for (int t = 0; t < TOPK; ++t) {
        float bv = val;
        int bi = myidx;
#pragma unroll
        for (int off = 32; off > 0; off >>= 1) {
            const float ov = __shfl_xor(bv, off);
            const int oi = __shfl_xor(bi, off);
            if (ov > bv || (ov == bv && oi < bi)) { bv = ov; bi = oi; }
        }
        sel[t] = bi;           // uniform across wave
        if (bi == myidx) val = -3e38f;  // remove from candidates
    }

    // ---- keep only causally-reachable blocks (rest are fully masked anyway) ----
    int vblk[TOPK];
    int nvb = 0;
#pragma unroll
    for (int t = 0; t < TOPK; ++t) {
        const int b = sel[t];
        if (b * BLOCK <= pos) vblk[nvb++] = b;
    }

    // ---- phase 1: scores for up to nvb*64 keys; lane r handles key b*64+r ----
    float m = -3e38f;
    for (int t = 0; t < nvb; ++t) {
        const int b = vblk[t];
        const int j = b * BLOCK + lane;
        float s = NEGV;
        if (j <= pos) {
            const float* kp = k + (size_t)j * KVDIM + kv * HD;
            float acc = 0.f;
#pragma unroll
            for (int d = 0; d < HD; d += 4) {
                const float4 qv = *reinterpret_cast<const float4*>(qp + d);
                const float4 kk4 = *reinterpret_cast<const float4*>(kp + d);
                acc += qv.x * kk4.x + qv.y * kk4.y + qv.z * kk4.z + qv.w * kk4.w;
            }
            s = acc * SCALE;
            if (s > m) m = s;
        }
        sc[t * BLOCK + lane] = s;
    }
#pragma unroll
    for (int off = 32; off > 0; off >>= 1) m = fmaxf(m, __shfl_xor(m, off));

    // ---- phase 2: exp + sum ----
    float lsum = 0.f;
    for (int t = 0; t < nvb; ++t) {
        const float s = sc[t * BLOCK + lane];
        const float e = (s > -1e29f) ? expf(s - m) : 0.f;
        sc[t * BLOCK + lane] = e;
        lsum += e;
    }
#pragma unroll
    for (int off = 32; off > 0; off >>= 1) lsum += __shfl_xor(lsum, off);
    const float inv = 1.f / lsum;

    __syncthreads();  // make cross-lane sc[] writes visible

    // ---- phase 3: O = P @ V ; lane owns dims 2*lane, 2*lane+1 ----
    float o0 = 0.f, o1 = 0.f;
    for (int t = 0; t < nvb; ++t) {
        const int b = vblk[t];
        const float* vbase = v + (size_t)(b * BLOCK) * KVDIM + kv * HD + 2 * lane;
        for (int r = 0; r < BLOCK; ++r) {
            const float p = sc[t * BLOCK + r];  // LDS broadcast
            const float2 vv = *reinterpret_cast<const float2*>(vbase + (size_t)r * KVDIM);
            o0 += p * vv.x;
            o1 += p * vv.y;
        }
    }
    float* op = attn_out + ((size_t)pos * NH + h) * HD + 2 * lane;
    op[0] = o0 * inv;
    op[1] = o1 * inv;
}

// ---------------- launch ----------------
extern "C" void kernel_launch(void* const* d_in, const int* in_sizes, int n_in,
                              void* d_out, int out_size, void* d_ws, size_t ws_size,
                              hipStream_t stream) {
    const float* x    = (const float*)d_in[0];
    const float* cosb = (const float*)d_in[1];
    const float* sinb = (const float*)d_in[2];
    const float* wq   = (const float*)d_in[3];
    const float* wk   = (const float*)d_in[4];
    const float* wv   = (const float*)d_in[5];
    const float* wo   = (const float*)d_in[6];

    float* ws   = (float*)d_ws;
    float* qf   = ws;                                    // 2048*4096
    float* kf   = qf + (size_t)SEQ * DIM;                // 2048*1024
    float* vf   = kf + (size_t)SEQ * KVDIM;              // 2048*1024
    float* kblk = vf + (size_t)SEQ * KVDIM;              // 8*32*128
    float* attn = kblk + (size_t)NKV * NBLK * HD;        // 2048*4096

    const dim3 t256(256);

    // QKV projections (fp32 out)
    gemm_kernel<<<dim3(DIM / 64, SEQ / 64), t256, 0, stream>>>(x, wq, qf, SEQ, DIM, DIM);
    gemm_kernel<<<dim3(KVDIM / 64, SEQ / 64), t256, 0, stream>>>(x, wk, kf, SEQ, KVDIM, DIM);
    gemm_kernel<<<dim3(KVDIM / 64, SEQ / 64), t256, 0, stream>>>(x, wv, vf, SEQ, KVDIM, DIM);

    // RoPE q and k (in place)
    rope_kernel<<<(SEQ * NH * 64) / 256, t256, 0, stream>>>(qf, cosb, sinb, NH);
    rope_kernel<<<(SEQ * NKV * 64) / 256, t256, 0, stream>>>(kf, cosb, sinb, NKV);

    // K block means
    blkmean_kernel<<<(NKV * NBLK * HD) / 256, t256, 0, stream>>>(kf, kblk);

    // Sparse attention
    attn_kernel<<<dim3(SEQ, NH), dim3(64), 0, stream>>>(qf, kf, vf, kblk, attn);

    // Output projection (fp32 out)
    gemm_kernel<<<dim3(DIM / 64, SEQ / 64), t256, 0, stream>>>(attn, wo, (float*)d_out, SEQ, DIM, DIM);
}

// Round 3
// 3861.032 us; speedup vs baseline: 1.3518x; 1.3518x over previous
//
#include <hip/hip_runtime.h>
#include <hip/hip_bf16.h>
#include <math.h>

#define SEQ 2048
#define DIM 4096
#define NH 32
#define HD 128
#define NKV 8
#define NREP 4
#define BLOCK 64
#define NBLK 32
#define TOPK 8
#define KVDIM (NKV * HD)   // 1024
#define SCALE 0.08838834764831845f

// ---------------- Tiled GEMM: C(MxN) = A(MxK) @ B(KxN), fp32 accumulate ----------------
__global__ __launch_bounds__(256) void gemm_kernel(const float* __restrict__ A,
                                                   const float* __restrict__ B,
                                                   float* __restrict__ C,
                                                   int M, int N, int K) {
    __shared__ __align__(16) float As[16][68];
    __shared__ __align__(16) float Bs[16][68];

    const int tid = threadIdx.x;
    const int bm = blockIdx.y * 64;
    const int bn = blockIdx.x * 64;
    const int tm = (tid >> 4) * 4;
    const int tn = (tid & 15) * 4;

    float acc[4][4] = {};

    for (int k0 = 0; k0 < K; k0 += 16) {
        {
            const int m = tid >> 2;
            const int kk = (tid & 3) * 4;
            const float* ap = A + (size_t)(bm + m) * K + k0 + kk;
            const float4 a4 = *reinterpret_cast<const float4*>(ap);
            As[kk + 0][m] = a4.x;
            As[kk + 1][m] = a4.y;
            As[kk + 2][m] = a4.z;
            As[kk + 3][m] = a4.w;
        }
        {
            const int kk = tid >> 4;
            const int n = (tid & 15) * 4;
            const float* bp = B + (size_t)(k0 + kk) * N + bn + n;
            *reinterpret_cast<float4*>(&Bs[kk][n]) = *reinterpret_cast<const float4*>(bp);
        }
        __syncthreads();
#pragma unroll
        for (int kk = 0; kk < 16; ++kk) {
            const float4 a4 = *reinterpret_cast<const float4*>(&As[kk][tm]);
            const float4 b4 = *reinterpret_cast<const float4*>(&Bs[kk][tn]);
            const float av[4] = {a4.x, a4.y, a4.z, a4.w};
            const float bv[4] = {b4.x, b4.y, b4.z, b4.w};
#pragma unroll
            for (int i = 0; i < 4; ++i)
#pragma unroll
                for (int j = 0; j < 4; ++j) acc[i][j] += av[i] * bv[j];
        }
        __syncthreads();
    }
#pragma unroll
    for (int i = 0; i < 4; ++i)
#pragma unroll
        for (int j = 0; j < 4; ++j)
            C[(size_t)(bm + tm + i) * N + bn + tn + j] = acc[i][j];
}

// ---------------- RoPE (in place, fp32 buffer) ----------------
__global__ void rope_kernel(float* __restrict__ x, const float* __restrict__ cosb,
                            const float* __restrict__ sinb, int nh) {
    const int idx = blockIdx.x * blockDim.x + threadIdx.x;
    const int i = idx & 63;
    const int h = (idx >> 6) % nh;
    const int pos = idx / (64 * nh);
    const float c = cosb[pos * 64 + i];
    const float s = sinb[pos * 64 + i];
    float* p = x + ((size_t)pos * nh + h) * HD + 2 * i;
    const float x0 = p[0], x1 = p[1];
    p[0] = x0 * c - x1 * s;
    p[1] = x0 * s + x1 * c;
}

// ---------------- Block means of K ----------------
__global__ void blkmean_kernel(const float* __restrict__ k, float* __restrict__ kblk) {
    const int idx = blockIdx.x * blockDim.x + threadIdx.x;
    const int d = idx & 127;
    const int blk = (idx >> 7) & 31;
    const int kv = idx >> 12;
    float s = 0.f;
#pragma unroll 8
    for (int r = 0; r < BLOCK; ++r)
        s += k[(size_t)(blk * BLOCK + r) * KVDIM + kv * HD + d];
    kblk[idx] = s * (1.f / 64.f);
}

// ---------------- bf16 helpers ----------------
__device__ inline unsigned short f2b(float f) {
    __hip_bfloat16 h = __float2bfloat16(f);
    return *reinterpret_cast<unsigned short*>(&h);
}
__device__ inline float bitsf(unsigned int u) {
    union { float f; unsigned int i; } x; x.i = u; return x.f;
}
__device__ inline void unpack2(unsigned int w0, float* o) {
    o[0] = bitsf(w0 << 16);
    o[1] = bitsf(w0 & 0xffff0000u);
}
__device__ inline void unpack4(uint2 w, float* o) {
    unpack2(w.x, o); unpack2(w.y, o + 2);
}
__device__ inline void unpack8(uint4 w, float* o) {
    unpack2(w.x, o); unpack2(w.y, o + 2); unpack2(w.z, o + 4); unpack2(w.w, o + 6);
}
__device__ inline float dot4f(float4 a, float4 b) {
    return a.x * b.x + a.y * b.y + a.z * b.z + a.w * b.w;
}

// ---------------- Flash-style sparse attention: one wg per (64-query tile, head) -----
// 256 threads = 4 waves. Per-wave lane layout: kl = lane&15 (key/dim patch), ql = lane>>4.
// Thread owns queries qi_r[i] = ql + 4*w + 16*i (i=0..3).
__global__ __launch_bounds__(256) void attn_tile_kernel(const float* __restrict__ q,
                                                        const float* __restrict__ k,
                                                        const float* __restrict__ v,
                                                        const float* __restrict__ kblk,
                                                        float* __restrict__ out) {
    __shared__ __align__(16) unsigned char smem[62464];
    // phase-2 layout (main loop), bf16 tiles
    unsigned short* ksb = (unsigned short*)smem;            // [64][136]
    unsigned short* vsb = (unsigned short*)(smem + 17408);  // [64][136]
    unsigned short* psb = (unsigned short*)(smem + 34816);  // [64][68]
    unsigned short* qsb = (unsigned short*)(smem + 43520);  // [64][136] -> ends 60928
    float* mrow = (float*)(smem + 60928);
    float* lrow = (float*)(smem + 61184);
    float* arow = (float*)(smem + 61440);
    float* mnew = (float*)(smem + 61696);
    unsigned int* selm = (unsigned int*)(smem + 61952);     // 64 x u32 -> ends 62208
    // phase-1 layout (selection), fp32 — aliases phase-2 tile regions (dead by then)
    float* qf  = (float*)smem;             // [64][132] -> ends 33792
    float* kbf = (float*)(smem + 33792);   // [32][132] -> ends 50688
    float* bsc = (float*)(smem + 50688);   // [64][33]  -> ends 59136

    const int qt = 31 - blockIdx.x;        // reverse: big tiles dispatched first
    const int h = blockIdx.y;
    const int kv = h >> 2;
    const int qbase = qt * 64;
    const int tid = threadIdx.x;
    const int lane = tid & 63;
    const int w = tid >> 6;
    const int kl = lane & 15;
    const int ql = lane >> 4;

    // ---- stage q tile (fp32) + kblk (fp32) ----
#pragma unroll
    for (int u = 0; u < 8; ++u) {
        const int idx = u * 1024 + tid * 4;
        const int qi = idx >> 7, d = idx & 127;
        *(float4*)(qf + qi * 132 + d) =
            *(const float4*)(q + ((size_t)((qbase + qi) * NH + h)) * HD + d);
    }
#pragma unroll
    for (int u = 0; u < 4; ++u) {
        const int idx = u * 1024 + tid * 4;
        const int b = idx >> 7, d = idx & 127;
        *(float4*)(kbf + b * 132 + d) =
            *(const float4*)(kblk + ((size_t)(kv * NBLK + b)) * HD + d);
    }
    __syncthreads();

    // ---- block scores (fp32): thread -> 4 queries x 2 blocks ----
    {
        float acc[4][2] = {};
#pragma unroll 4
        for (int d = 0; d < 128; d += 4) {
            float4 qv[4], kb2[2];
#pragma unroll
            for (int i = 0; i < 4; ++i) qv[i] = *(float4*)(qf + (ql + 4 * w + 16 * i) * 132 + d);
#pragma unroll
            for (int j = 0; j < 2; ++j) kb2[j] = *(float4*)(kbf + (kl + 16 * j) * 132 + d);
#pragma unroll
            for (int i = 0; i < 4; ++i)
#pragma unroll
                for (int j = 0; j < 2; ++j) acc[i][j] += dot4f(qv[i], kb2[j]);
        }
#pragma unroll
        for (int i = 0; i < 4; ++i)
#pragma unroll
            for (int j = 0; j < 2; ++j) {
                const int b = kl + 16 * j;
                if (b <= qt) bsc[(ql + 4 * w + 16 * i) * 33 + b] = acc[i][j];
            }
    }
    __syncthreads();

    // ---- per-query top-min(8,qt+1), ties -> lower index (matches jax.lax.top_k) ----
    if (tid < 64) {
        const int ns = (qt + 1 < TOPK) ? qt + 1 : TOPK;
        unsigned int sel = 0;
        const float* br = bsc + tid * 33;
        for (int t = 0; t < ns; ++t) {
            float best = -3.4e38f; int bi = 0;
            for (int b = 0; b <= qt; ++b)
                if (!((sel >> b) & 1u) && br[b] > best) { best = br[b]; bi = b; }
            sel |= 1u << bi;
        }
        selm[tid] = sel;
        mrow[tid] = -3.0e38f;
        lrow[tid] = 0.f;
    }
    __syncthreads();

    // ---- union mask + convert q tile to bf16 (qsb region clobbers bsc: dead) ----
    unsigned int uni = 0;
    {
        float tmp[32];
#pragma unroll
        for (int u = 0; u < 8; ++u) {
            const int idx = u * 1024 + tid * 4;
            *(float4*)(tmp + u * 4) = *(float4*)(qf + (idx >> 7) * 132 + (idx & 127));
        }
        for (int i = 0; i < 64; ++i) uni |= selm[i];
#pragma unroll
        for (int u = 0; u < 8; ++u) {
            const int idx = u * 1024 + tid * 4;
            const int qi = idx >> 7, d = idx & 127;
            ushort4 qu;
            qu.x = f2b(tmp[u * 4 + 0]); qu.y = f2b(tmp[u * 4 + 1]);
            qu.z = f2b(tmp[u * 4 + 2]); qu.w = f2b(tmp[u * 4 + 3]);
            *(ushort4*)(qsb + qi * 136 + d) = qu;
        }
    }
    __syncthreads();

    const int qi_r[4] = {ql + 4 * w, ql + 4 * w + 16, ql + 4 * w + 32, ql + 4 * w + 48};
    unsigned int selq[4];
#pragma unroll
    for (int i = 0; i < 4; ++i) selq[i] = selm[qi_r[i]];

    float O[4][8] = {};

    for (int b = 0; b <= qt; ++b) {
        if (!((uni >> b) & 1u)) continue;
        __syncthreads();  // previous tile's ks/vs/ps readers done
        // ---- stage K/V block b as bf16 ----
#pragma unroll
        for (int u = 0; u < 8; ++u) {
            const int idx = u * 1024 + tid * 4;
            const int r = idx >> 7, d = idx & 127;
            const size_t gof = (size_t)(b * 64 + r) * KVDIM + kv * HD + d;
            const float4 k4 = *(const float4*)(k + gof);
            const float4 v4 = *(const float4*)(v + gof);
            ushort4 ku, vu;
            ku.x = f2b(k4.x); ku.y = f2b(k4.y); ku.z = f2b(k4.z); ku.w = f2b(k4.w);
            vu.x = f2b(v4.x); vu.y = f2b(v4.y); vu.z = f2b(v4.z); vu.w = f2b(v4.w);
            *(ushort4*)(ksb + r * 136 + d) = ku;
            *(ushort4*)(vsb + r * 136 + d) = vu;
        }
        __syncthreads();

        // ---- QK: 4q x 4k patch per thread ----
        float S[4][4] = {};
#pragma unroll 4
        for (int d = 0; d < 128; d += 4) {
            float qv[4][4], kk4[4][4];
#pragma unroll
            for (int i = 0; i < 4; ++i) unpack4(*(uint2*)(qsb + qi_r[i] * 136 + d), qv[i]);
#pragma unroll
            for (int j = 0; j < 4; ++j) unpack4(*(uint2*)(ksb + (kl + 16 * j) * 136 + d), kk4[j]);
#pragma unroll
            for (int i = 0; i < 4; ++i)
#pragma unroll
                for (int j = 0; j < 4; ++j)
#pragma unroll
                    for (int e = 0; e < 4; ++e) S[i][j] += qv[i][e] * kk4[j][e];
        }

        // ---- mask, scale, row-max (reduce over the 16 kl-lanes) ----
        const bool diag = (b == qt);
        float tm[4];
#pragma unroll
        for (int i = 0; i < 4; ++i) {
            const bool selb = (selq[i] >> b) & 1u;
#pragma unroll
            for (int j = 0; j < 4; ++j) {
                const int kj = kl + 16 * j;
                const bool valid = selb && (!diag || kj <= qi_r[i]);
                S[i][j] = valid ? S[i][j] * SCALE : -3.0e38f;
            }
            float t = fmaxf(fmaxf(S[i][0], S[i][1]), fmaxf(S[i][2], S[i][3]));
            t = fmaxf(t, __shfl_xor(t, 1));
            t = fmaxf(t, __shfl_xor(t, 2));
            t = fmaxf(t, __shfl_xor(t, 4));
            t = fmaxf(t, __shfl_xor(t, 8));
            tm[i] = t;
        }
        if (kl == 0) {
#pragma unroll
            for (int i = 0; i < 4; ++i) {
                const float mo = mrow[qi_r[i]];
                const float mn = fmaxf(mo, tm[i]);
                mrow[qi_r[i]] = mn;
                mnew[qi_r[i]] = mn;
                arow[qi_r[i]] = __expf(mo - mn);
            }
        }
        __syncthreads();

        // ---- P = exp(S - mnew), row-sum, write psb (bf16) ----
        float tl[4];
#pragma unroll
        for (int i = 0; i < 4; ++i) {
            const float mn = mnew[qi_r[i]];
            float sum = 0.f;
#pragma unroll
            for (int j = 0; j < 4; ++j) {
                const float p = (S[i][j] > -1.0e30f) ? __expf(S[i][j] - mn) : 0.f;
                psb[qi_r[i] * 68 + kl + 16 * j] = f2b(p);
                sum += p;
            }
            sum += __shfl_xor(sum, 1);
            sum += __shfl_xor(sum, 2);
            sum += __shfl_xor(sum, 4);
            sum += __shfl_xor(sum, 8);
            tl[i] = sum;
        }
        if (kl == 0) {
#pragma unroll
            for (int i = 0; i < 4; ++i)
                lrow[qi_r[i]] = lrow[qi_r[i]] * arow[qi_r[i]] + tl[i];
        }
        // ---- rescale O by alpha (arow valid since previous barrier) ----
#pragma unroll
        for (int i = 0; i < 4; ++i) {
            const float a = arow[qi_r[i]];
#pragma unroll
            for (int e = 0; e < 8; ++e) O[i][e] *= a;
        }
        __syncthreads();  // psb visible

        // ---- PV: 4q x 8d patch per thread, d_off = kl*8 ----
#pragma unroll 4
        for (int kj = 0; kj < 64; ++kj) {
            float p[4];
#pragma unroll
            for (int i = 0; i < 4; ++i) {
                unsigned short us = psb[qi_r[i] * 68 + kj];
                p[i] = bitsf(((unsigned int)us) << 16);
            }
            float vv[8];
            unpack8(*(uint4*)(vsb + kj * 136 + kl * 8), vv);
#pragma unroll
            for (int i = 0; i < 4; ++i)
#pragma unroll
                for (int e = 0; e < 8; ++e) O[i][e] += p[i] * vv[e];
        }
    }
    __syncthreads();  // lrow final visible

    // ---- normalize + store ----
#pragma unroll
    for (int i = 0; i < 4; ++i) {
        const float inv = 1.f / lrow[qi_r[i]];
        float4 o0, o1;
        o0.x = O[i][0] * inv; o0.y = O[i][1] * inv; o0.z = O[i][2] * inv; o0.w = O[i][3] * inv;
        o1.x = O[i][4] * inv; o1.y = O[i][5] * inv; o1.z = O[i][6] * inv; o1.w = O[i][7] * inv;
        float* op = out + ((size_t)((qbase + qi_r[i]) * NH + h)) * HD + kl * 8;
        *(float4*)op = o0;
        *(float4*)(op + 4) = o1;
    }
}

// ---------------- launch ----------------
extern "C" void kernel_launch(void* const* d_in, const int* in_sizes, int n_in,
                              void* d_out, int out_size, void* d_ws, size_t ws_size,
                              hipStream_t stream) {
    const float* x    = (const float*)d_in[0];
    const float* cosb = (const float*)d_in[1];
    const float* sinb = (const float*)d_in[2];
    const float* wq   = (const float*)d_in[3];
    const float* wk   = (const float*)d_in[4];
    const float* wv   = (const float*)d_in[5];
    const float* wo   = (const float*)d_in[6];

    float* ws   = (float*)d_ws;
    float* qf   = ws;                                    // 2048*4096
    float* kf   = qf + (size_t)SEQ * DIM;                // 2048*1024
    float* vf   = kf + (size_t)SEQ * KVDIM;              // 2048*1024
    float* kblk = vf + (size_t)SEQ * KVDIM;              // 8*32*128
    float* attn = kblk + (size_t)NKV * NBLK * HD;        // 2048*4096

    const dim3 t256(256);

    gemm_kernel<<<dim3(DIM / 64, SEQ / 64), t256, 0, stream>>>(x, wq, qf, SEQ, DIM, DIM);
    gemm_kernel<<<dim3(KVDIM / 64, SEQ / 64), t256, 0, stream>>>(x, wk, kf, SEQ, KVDIM, DIM);
    gemm_kernel<<<dim3(KVDIM / 64, SEQ / 64), t256, 0, stream>>>(x, wv, vf, SEQ, KVDIM, DIM);

    rope_kernel<<<(SEQ * NH * 64) / 256, t256, 0, stream>>>(qf, cosb, sinb, NH);
    rope_kernel<<<(SEQ * NKV * 64) / 256, t256, 0, stream>>>(kf, cosb, sinb, NKV);

    blkmean_kernel<<<(NKV * NBLK * HD) / 256, t256, 0, stream>>>(kf, kblk);

    attn_tile_kernel<<<dim3(NBLK, NH), t256, 0, stream>>>(qf, kf, vf, kblk, attn);

    gemm_kernel<<<dim3(DIM / 64, SEQ / 64), t256, 0, stream>>>(attn, wo, (float*)d_out, SEQ, DIM, DIM);
}

// Round 4
// 1930.606 us; speedup vs baseline: 2.7034x; 1.9999x over previous
//
#include <hip/hip_runtime.h>
#include <hip/hip_bf16.h>
#include <math.h>

#define SEQ 2048
#define DIM 4096
#define NH 32
#define HD 128
#define NKV 8
#define NREP 4
#define BLOCK 64
#define NBLK 32
#define TOPK 8
#define KVDIM (NKV * HD)   // 1024
#define SCALE 0.08838834764831845f

// ---------------- bf16 helpers ----------------
__device__ inline unsigned short f2b(float f) {
    __hip_bfloat16 h = __float2bfloat16(f);
    return *reinterpret_cast<unsigned short*>(&h);
}
__device__ inline float bitsf(unsigned int u) {
    union { float f; unsigned int i; } x; x.i = u; return x.f;
}
__device__ inline float b2f(unsigned short us) { return bitsf(((unsigned int)us) << 16); }
__device__ inline void unpack2(unsigned int w0, float* o) {
    o[0] = bitsf(w0 << 16);
    o[1] = bitsf(w0 & 0xffff0000u);
}
__device__ inline void unpack4(uint2 w, float* o) { unpack2(w.x, o); unpack2(w.y, o + 2); }
__device__ inline void unpack8(uint4 w, float* o) {
    unpack2(w.x, o); unpack2(w.y, o + 2); unpack2(w.z, o + 4); unpack2(w.w, o + 6);
}
__device__ inline float dot4f(float4 a, float4 b) {
    return a.x * b.x + a.y * b.y + a.z * b.z + a.w * b.w;
}

// ---------------- MFMA GEMM: C(MxN) = A(MxK) @ Bt(NxK)^T, bf16 in / fp32 out -------
// 128x128 tile, BK=32, 256 threads = 4 waves, each wave 64x64 via 4x4 mfma_16x16x32.
// SPLIT: A = Ah + Al, B = Bh + Bl (bf16 pairs); acc = AhBh + AhBl + AlBh (~fp32 accurate).
typedef __attribute__((ext_vector_type(8))) short bfrag;
typedef __attribute__((ext_vector_type(4))) float ffrag;

__device__ __forceinline__ void gl_lds16(const void* g, void* l) {
    __builtin_amdgcn_global_load_lds((const __attribute__((address_space(1))) void*)g,
                                     (__attribute__((address_space(3))) void*)l, 16, 0, 0);
}

template <bool SPLIT>
__global__ __launch_bounds__(256) void mfma_gemm(const unsigned short* __restrict__ Ah,
                                                 const unsigned short* __restrict__ Al,
                                                 const unsigned short* __restrict__ Bh,
                                                 const unsigned short* __restrict__ Bl,
                                                 float* __restrict__ C,
                                                 int M, int N, int K) {
    __shared__ short As[(SPLIT ? 2 : 1) * 4096];  // [hi(,lo)][128][32]
    __shared__ short Bs[(SPLIT ? 2 : 1) * 4096];

    const int tid = threadIdx.x;
    const int lane = tid & 63;
    const int w = tid >> 6;
    const int wm = (w >> 1) * 64;
    const int wn = (w & 1) * 64;
    const int m = lane & 15;
    const int quad = lane >> 4;
    const int bm = blockIdx.y * 128;
    const int bn = blockIdx.x * 128;

    // staging: element idx = u*2048 + tid*8 -> tile(row=idx>>5, col=idx&31)
    const int r0 = tid >> 2;
    const int c0 = (tid & 3) * 8;
    const size_t aoff0 = (size_t)(bm + r0) * K + c0;
    const size_t aoff1 = (size_t)(bm + r0 + 64) * K + c0;
    const size_t boff0 = (size_t)(bn + r0) * K + c0;
    const size_t boff1 = (size_t)(bn + r0 + 64) * K + c0;

    ffrag acc[4][4];
    const ffrag z = {0.f, 0.f, 0.f, 0.f};
#pragma unroll
    for (int i = 0; i < 4; ++i)
#pragma unroll
        for (int j = 0; j < 4; ++j) acc[i][j] = z;

    for (int kt = 0; kt < K; kt += 32) {
        __syncthreads();
        gl_lds16(Ah + aoff0 + kt, As + tid * 8);
        gl_lds16(Ah + aoff1 + kt, As + 2048 + tid * 8);
        gl_lds16(Bh + boff0 + kt, Bs + tid * 8);
        gl_lds16(Bh + boff1 + kt, Bs + 2048 + tid * 8);
        if constexpr (SPLIT) {
            gl_lds16(Al + aoff0 + kt, As + 4096 + tid * 8);
            gl_lds16(Al + aoff1 + kt, As + 6144 + tid * 8);
            gl_lds16(Bl + boff0 + kt, Bs + 4096 + tid * 8);
            gl_lds16(Bl + boff1 + kt, Bs + 6144 + tid * 8);
        }
        __syncthreads();

        bfrag ah[4], bh[4];
#pragma unroll
        for (int i = 0; i < 4; ++i)
            ah[i] = *(const bfrag*)(As + (wm + i * 16 + m) * 32 + quad * 8);
#pragma unroll
        for (int j = 0; j < 4; ++j)
            bh[j] = *(const bfrag*)(Bs + (wn + j * 16 + m) * 32 + quad * 8);
        if constexpr (SPLIT) {
            bfrag al[4], bl[4];
#pragma unroll
            for (int i = 0; i < 4; ++i)
                al[i] = *(const bfrag*)(As + 4096 + (wm + i * 16 + m) * 32 + quad * 8);
#pragma unroll
            for (int j = 0; j < 4; ++j)
                bl[j] = *(const bfrag*)(Bs + 4096 + (wn + j * 16 + m) * 32 + quad * 8);
#pragma unroll
            for (int i = 0; i < 4; ++i)
#pragma unroll
                for (int j = 0; j < 4; ++j) {
                    acc[i][j] = __builtin_amdgcn_mfma_f32_16x16x32_bf16(ah[i], bh[j], acc[i][j], 0, 0, 0);
                    acc[i][j] = __builtin_amdgcn_mfma_f32_16x16x32_bf16(ah[i], bl[j], acc[i][j], 0, 0, 0);
                    acc[i][j] = __builtin_amdgcn_mfma_f32_16x16x32_bf16(al[i], bh[j], acc[i][j], 0, 0, 0);
                }
        } else {
#pragma unroll
            for (int i = 0; i < 4; ++i)
#pragma unroll
                for (int j = 0; j < 4; ++j)
                    acc[i][j] = __builtin_amdgcn_mfma_f32_16x16x32_bf16(ah[i], bh[j], acc[i][j], 0, 0, 0);
        }
    }

#pragma unroll
    for (int i = 0; i < 4; ++i)
#pragma unroll
        for (int j = 0; j < 4; ++j)
#pragma unroll
            for (int r = 0; r < 4; ++r)
                C[(size_t)(bm + wm + i * 16 + quad * 4 + r) * N + bn + wn + j * 16 + m] =
                    acc[i][j][r];
}

// ---------------- transpose + bf16 split: W(KxN fp32) -> T(NxK bf16 hi[,lo]) --------
__global__ __launch_bounds__(256) void transpose_conv(const float* __restrict__ W,
                                                      unsigned short* __restrict__ Th,
                                                      unsigned short* __restrict__ Tl,
                                                      int K, int N, int rowoff) {
    __shared__ float tile[32][36];
    const int k0 = blockIdx.y * 32, n0 = blockIdx.x * 32;
    const int t = threadIdx.x;
    const int r = t >> 3, c4 = (t & 7) * 4;
    *(float4*)&tile[r][c4] = *(const float4*)(W + (size_t)(k0 + r) * N + n0 + c4);
    __syncthreads();
    float v0 = tile[c4 + 0][r], v1 = tile[c4 + 1][r], v2 = tile[c4 + 2][r], v3 = tile[c4 + 3][r];
    ushort4 h;
    h.x = f2b(v0); h.y = f2b(v1); h.z = f2b(v2); h.w = f2b(v3);
    const size_t ooff = (size_t)(rowoff + n0 + r) * K + k0 + c4;
    *(ushort4*)(Th + ooff) = h;
    if (Tl) {
        ushort4 l;
        l.x = f2b(v0 - b2f(h.x)); l.y = f2b(v1 - b2f(h.y));
        l.z = f2b(v2 - b2f(h.z)); l.w = f2b(v3 - b2f(h.w));
        *(ushort4*)(Tl + ooff) = l;
    }
}

// ---------------- elementwise fp32 -> bf16 hi (+lo) ----------------
__global__ void conv_hilo(const float* __restrict__ X, unsigned short* __restrict__ H,
                          unsigned short* __restrict__ L) {
    const int i = (blockIdx.x * blockDim.x + threadIdx.x) * 4;
    const float4 x = *(const float4*)(X + i);
    ushort4 h;
    h.x = f2b(x.x); h.y = f2b(x.y); h.z = f2b(x.z); h.w = f2b(x.w);
    *(ushort4*)(H + i) = h;
    if (L) {
        ushort4 l;
        l.x = f2b(x.x - b2f(h.x)); l.y = f2b(x.y - b2f(h.y));
        l.z = f2b(x.z - b2f(h.z)); l.w = f2b(x.w - b2f(h.w));
        *(ushort4*)(L + i) = l;
    }
}

// ---------------- fallback fp32 GEMM (R2/R3 proven) ----------------
__global__ __launch_bounds__(256) void gemm_kernel(const float* __restrict__ A,
                                                   const float* __restrict__ B,
                                                   float* __restrict__ C,
                                                   int M, int N, int K) {
    __shared__ __align__(16) float As[16][68];
    __shared__ __align__(16) float Bs[16][68];

    const int tid = threadIdx.x;
    const int bm = blockIdx.y * 64;
    const int bn = blockIdx.x * 64;
    const int tm = (tid >> 4) * 4;
    const int tn = (tid & 15) * 4;

    float acc[4][4] = {};

    for (int k0 = 0; k0 < K; k0 += 16) {
        {
            const int mm = tid >> 2;
            const int kk = (tid & 3) * 4;
            const float* ap = A + (size_t)(bm + mm) * K + k0 + kk;
            const float4 a4 = *reinterpret_cast<const float4*>(ap);
            As[kk + 0][mm] = a4.x;
            As[kk + 1][mm] = a4.y;
            As[kk + 2][mm] = a4.z;
            As[kk + 3][mm] = a4.w;
        }
        {
            const int kk = tid >> 4;
            const int n = (tid & 15) * 4;
            const float* bp = B + (size_t)(k0 + kk) * N + bn + n;
            *reinterpret_cast<float4*>(&Bs[kk][n]) = *reinterpret_cast<const float4*>(bp);
        }
        __syncthreads();
#pragma unroll
        for (int kk = 0; kk < 16; ++kk) {
            const float4 a4 = *reinterpret_cast<const float4*>(&As[kk][tm]);
            const float4 b4 = *reinterpret_cast<const float4*>(&Bs[kk][tn]);
            const float av[4] = {a4.x, a4.y, a4.z, a4.w};
            const float bv[4] = {b4.x, b4.y, b4.z, b4.w};
#pragma unroll
            for (int i = 0; i < 4; ++i)
#pragma unroll
                for (int j = 0; j < 4; ++j) acc[i][j] += av[i] * bv[j];
        }
        __syncthreads();
    }
#pragma unroll
    for (int i = 0; i < 4; ++i)
#pragma unroll
        for (int j = 0; j < 4; ++j)
            C[(size_t)(bm + tm + i) * N + bn + tn + j] = acc[i][j];
}

// ---------------- RoPE (in place, fp32 buffer; row stride param) ----------------
__global__ void rope_kernel(float* __restrict__ x, const float* __restrict__ cosb,
                            const float* __restrict__ sinb, int nh, int stride) {
    const int idx = blockIdx.x * blockDim.x + threadIdx.x;
    const int i = idx & 63;
    const int h = (idx >> 6) % nh;
    const int pos = idx / (64 * nh);
    const float c = cosb[pos * 64 + i];
    const float s = sinb[pos * 64 + i];
    float* p = x + (size_t)pos * stride + h * HD + 2 * i;
    const float x0 = p[0], x1 = p[1];
    p[0] = x0 * c - x1 * s;
    p[1] = x0 * s + x1 * c;
}

// ---------------- Block means of K ----------------
__global__ void blkmean_kernel(const float* __restrict__ k, float* __restrict__ kblk,
                               int stride) {
    const int idx = blockIdx.x * blockDim.x + threadIdx.x;
    const int d = idx & 127;
    const int blk = (idx >> 7) & 31;
    const int kv = idx >> 12;
    float s = 0.f;
#pragma unroll 8
    for (int r = 0; r < BLOCK; ++r)
        s += k[(size_t)(blk * BLOCK + r) * stride + kv * HD + d];
    kblk[idx] = s * (1.f / 64.f);
}

// ---------------- Flash-style sparse attention (R3 proven; stride-param K/V) --------
__global__ __launch_bounds__(256) void attn_tile_kernel(const float* __restrict__ q,
                                                        const float* __restrict__ kptr,
                                                        const float* __restrict__ vptr,
                                                        const float* __restrict__ kblk,
                                                        float* __restrict__ out,
                                                        int kvstride) {
    __shared__ __align__(16) unsigned char smem[62464];
    unsigned short* ksb = (unsigned short*)smem;            // [64][136]
    unsigned short* vsb = (unsigned short*)(smem + 17408);  // [64][136]
    unsigned short* psb = (unsigned short*)(smem + 34816);  // [64][68]
    unsigned short* qsb = (unsigned short*)(smem + 43520);  // [64][136]
    float* mrow = (float*)(smem + 60928);
    float* lrow = (float*)(smem + 61184);
    float* arow = (float*)(smem + 61440);
    float* mnew = (float*)(smem + 61696);
    unsigned int* selm = (unsigned int*)(smem + 61952);
    float* qf  = (float*)smem;             // [64][132]
    float* kbf = (float*)(smem + 33792);   // [32][132]
    float* bsc = (float*)(smem + 50688);   // [64][33]

    const int qt = 31 - blockIdx.x;
    const int h = blockIdx.y;
    const int kv = h >> 2;
    const int qbase = qt * 64;
    const int tid = threadIdx.x;
    const int lane = tid & 63;
    const int w = tid >> 6;
    const int kl = lane & 15;
    const int ql = lane >> 4;

#pragma unroll
    for (int u = 0; u < 8; ++u) {
        const int idx = u * 1024 + tid * 4;
        const int qi = idx >> 7, d = idx & 127;
        *(float4*)(qf + qi * 132 + d) =
            *(const float4*)(q + ((size_t)((qbase + qi) * NH + h)) * HD + d);
    }
#pragma unroll
    for (int u = 0; u < 4; ++u) {
        const int idx = u * 1024 + tid * 4;
        const int b = idx >> 7, d = idx & 127;
        *(float4*)(kbf + b * 132 + d) =
            *(const float4*)(kblk + ((size_t)(kv * NBLK + b)) * HD + d);
    }
    __syncthreads();

    {
        float acc[4][2] = {};
#pragma unroll 4
        for (int d = 0; d < 128; d += 4) {
            float4 qv[4], kb2[2];
#pragma unroll
            for (int i = 0; i < 4; ++i) qv[i] = *(float4*)(qf + (ql + 4 * w + 16 * i) * 132 + d);
#pragma unroll
            for (int j = 0; j < 2; ++j) kb2[j] = *(float4*)(kbf + (kl + 16 * j) * 132 + d);
#pragma unroll
            for (int i = 0; i < 4; ++i)
#pragma unroll
                for (int j = 0; j < 2; ++j) acc[i][j] += dot4f(qv[i], kb2[j]);
        }
#pragma unroll
        for (int i = 0; i < 4; ++i)
#pragma unroll
            for (int j = 0; j < 2; ++j) {
                const int b = kl + 16 * j;
                if (b <= qt) bsc[(ql + 4 * w + 16 * i) * 33 + b] = acc[i][j];
            }
    }
    __syncthreads();

    if (tid < 64) {
        const int ns = (qt + 1 < TOPK) ? qt + 1 : TOPK;
        unsigned int sel = 0;
        const float* br = bsc + tid * 33;
        for (int t = 0; t < ns; ++t) {
            float best = -3.4e38f; int bi = 0;
            for (int b = 0; b <= qt; ++b)
                if (!((sel >> b) & 1u) && br[b] > best) { best = br[b]; bi = b; }
            sel |= 1u << bi;
        }
        selm[tid] = sel;
        mrow[tid] = -3.0e38f;
        lrow[tid] = 0.f;
    }
    __syncthreads();

    unsigned int uni = 0;
    {
        float tmp[32];
#pragma unroll
        for (int u = 0; u < 8; ++u) {
            const int idx = u * 1024 + tid * 4;
            *(float4*)(tmp + u * 4) = *(float4*)(qf + (idx >> 7) * 132 + (idx & 127));
        }
        for (int i = 0; i < 64; ++i) uni |= selm[i];
#pragma unroll
        for (int u = 0; u < 8; ++u) {
            const int idx = u * 1024 + tid * 4;
            const int qi = idx >> 7, d = idx & 127;
            ushort4 qu;
            qu.x = f2b(tmp[u * 4 + 0]); qu.y = f2b(tmp[u * 4 + 1]);
            qu.z = f2b(tmp[u * 4 + 2]); qu.w = f2b(tmp[u * 4 + 3]);
            *(ushort4*)(qsb + qi * 136 + d) = qu;
        }
    }
    __syncthreads();

    const int qi_r[4] = {ql + 4 * w, ql + 4 * w + 16, ql + 4 * w + 32, ql + 4 * w + 48};
    unsigned int selq[4];
#pragma unroll
    for (int i = 0; i < 4; ++i) selq[i] = selm[qi_r[i]];

    float O[4][8] = {};

    for (int b = 0; b <= qt; ++b) {
        if (!((uni >> b) & 1u)) continue;
        __syncthreads();
#pragma unroll
        for (int u = 0; u < 8; ++u) {
            const int idx = u * 1024 + tid * 4;
            const int r = idx >> 7, d = idx & 127;
            const size_t gof = (size_t)(b * 64 + r) * kvstride + kv * HD + d;
            const float4 k4 = *(const float4*)(kptr + gof);
            const float4 v4 = *(const float4*)(vptr + gof);
            ushort4 ku, vu;
            ku.x = f2b(k4.x); ku.y = f2b(k4.y); ku.z = f2b(k4.z); ku.w = f2b(k4.w);
            vu.x = f2b(v4.x); vu.y = f2b(v4.y); vu.z = f2b(v4.z); vu.w = f2b(v4.w);
            *(ushort4*)(ksb + r * 136 + d) = ku;
            *(ushort4*)(vsb + r * 136 + d) = vu;
        }
        __syncthreads();

        float S[4][4] = {};
#pragma unroll 4
        for (int d = 0; d < 128; d += 4) {
            float qv[4][4], kk4[4][4];
#pragma unroll
            for (int i = 0; i < 4; ++i) unpack4(*(uint2*)(qsb + qi_r[i] * 136 + d), qv[i]);
#pragma unroll
            for (int j = 0; j < 4; ++j) unpack4(*(uint2*)(ksb + (kl + 16 * j) * 136 + d), kk4[j]);
#pragma unroll
            for (int i = 0; i < 4; ++i)
#pragma unroll
                for (int j = 0; j < 4; ++j)
#pragma unroll
                    for (int e = 0; e < 4; ++e) S[i][j] += qv[i][e] * kk4[j][e];
        }

        const bool diag = (b == qt);
        float tm[4];
#pragma unroll
        for (int i = 0; i < 4; ++i) {
            const bool selb = (selq[i] >> b) & 1u;
#pragma unroll
            for (int j = 0; j < 4; ++j) {
                const int kj = kl + 16 * j;
                const bool valid = selb && (!diag || kj <= qi_r[i]);
                S[i][j] = valid ? S[i][j] * SCALE : -3.0e38f;
            }
            float t = fmaxf(fmaxf(S[i][0], S[i][1]), fmaxf(S[i][2], S[i][3]));
            t = fmaxf(t, __shfl_xor(t, 1));
            t = fmaxf(t, __shfl_xor(t, 2));
            t = fmaxf(t, __shfl_xor(t, 4));
            t = fmaxf(t, __shfl_xor(t, 8));
            tm[i] = t;
        }
        if (kl == 0) {
#pragma unroll
            for (int i = 0; i < 4; ++i) {
                const float mo = mrow[qi_r[i]];
                const float mn = fmaxf(mo, tm[i]);
                mrow[qi_r[i]] = mn;
                mnew[qi_r[i]] = mn;
                arow[qi_r[i]] = __expf(mo - mn);
            }
        }
        __syncthreads();

        float tl[4];
#pragma unroll
        for (int i = 0; i < 4; ++i) {
            const float mn = mnew[qi_r[i]];
            float sum = 0.f;
#pragma unroll
            for (int j = 0; j < 4; ++j) {
                const float p = (S[i][j] > -1.0e30f) ? __expf(S[i][j] - mn) : 0.f;
                psb[qi_r[i] * 68 + kl + 16 * j] = f2b(p);
                sum += p;
            }
            sum += __shfl_xor(sum, 1);
            sum += __shfl_xor(sum, 2);
            sum += __shfl_xor(sum, 4);
            sum += __shfl_xor(sum, 8);
            tl[i] = sum;
        }
        if (kl == 0) {
#pragma unroll
            for (int i = 0; i < 4; ++i)
                lrow[qi_r[i]] = lrow[qi_r[i]] * arow[qi_r[i]] + tl[i];
        }
#pragma unroll
        for (int i = 0; i < 4; ++i) {
            const float a = arow[qi_r[i]];
#pragma unroll
            for (int e = 0; e < 8; ++e) O[i][e] *= a;
        }
        __syncthreads();

#pragma unroll 4
        for (int kj = 0; kj < 64; ++kj) {
            float p[4];
#pragma unroll
            for (int i = 0; i < 4; ++i) {
                unsigned short us = psb[qi_r[i] * 68 + kj];
                p[i] = bitsf(((unsigned int)us) << 16);
            }
            float vv[8];
            unpack8(*(uint4*)(vsb + kj * 136 + kl * 8), vv);
#pragma unroll
            for (int i = 0; i < 4; ++i)
#pragma unroll
                for (int e = 0; e < 8; ++e) O[i][e] += p[i] * vv[e];
        }
    }
    __syncthreads();

#pragma unroll
    for (int i = 0; i < 4; ++i) {
        const float inv = 1.f / lrow[qi_r[i]];
        float4 o0, o1;
        o0.x = O[i][0] * inv; o0.y = O[i][1] * inv; o0.z = O[i][2] * inv; o0.w = O[i][3] * inv;
        o1.x = O[i][4] * inv; o1.y = O[i][5] * inv; o1.z = O[i][6] * inv; o1.w = O[i][7] * inv;
        float* op = out + ((size_t)((qbase + qi_r[i]) * NH + h)) * HD + kl * 8;
        *(float4*)op = o0;
        *(float4*)(op + 4) = o1;
    }
}

// ---------------- launch ----------------
extern "C" void kernel_launch(void* const* d_in, const int* in_sizes, int n_in,
                              void* d_out, int out_size, void* d_ws, size_t ws_size,
                              hipStream_t stream) {
    const float* x    = (const float*)d_in[0];
    const float* cosb = (const float*)d_in[1];
    const float* sinb = (const float*)d_in[2];
    const float* wq   = (const float*)d_in[3];
    const float* wk   = (const float*)d_in[4];
    const float* wv   = (const float*)d_in[5];
    const float* wo   = (const float*)d_in[6];

    unsigned char* ws = (unsigned char*)d_ws;
    const dim3 t256(256);

    const size_t MAIN_REQ = 184680448ull;  // 176 MB layout below
    if (ws_size >= MAIN_REQ) {
        // ---- main path: MFMA GEMMs ----
        float*          qf     = (float*)(ws);                       // 32 MB
        float*          kvf    = (float*)(ws + 33554432ull);         // 16 MB (k cols 0..1023, v 1024..2047)
        float*          kblk   = (float*)(ws + 50331648ull);         // 128 KB
        unsigned short* x_hi   = (unsigned short*)(ws + 50462720ull); // 16 MB
        unsigned short* x_lo   = (unsigned short*)(ws + 67239936ull); // 16 MB
        float*          attn   = (float*)(ws + 50462720ull);          // 32 MB (aliases x_hi+x_lo; x dead)
        unsigned short* wqT_hi = (unsigned short*)(ws + 84017152ull); // 32 MB (later woT_hi)
        unsigned short* wqT_lo = (unsigned short*)(ws + 117571584ull);// 32 MB (later attn_bf)
        unsigned short* kvT_hi = (unsigned short*)(ws + 151126016ull);// 16 MB
        unsigned short* kvT_lo = (unsigned short*)(ws + 167903232ull);// 16 MB
        unsigned short* woT_hi = wqT_hi;
        unsigned short* attnbf = wqT_lo;

        // x -> hi/lo bf16
        conv_hilo<<<SEQ * DIM / 4 / 256, t256, 0, stream>>>(x, x_hi, x_lo);
        // weight transposes (N x K, K=4096)
        transpose_conv<<<dim3(DIM / 32, DIM / 32), t256, 0, stream>>>(wq, wqT_hi, wqT_lo, DIM, DIM, 0);
        transpose_conv<<<dim3(KVDIM / 32, DIM / 32), t256, 0, stream>>>(wk, kvT_hi, kvT_lo, DIM, KVDIM, 0);
        transpose_conv<<<dim3(KVDIM / 32, DIM / 32), t256, 0, stream>>>(wv, kvT_hi, kvT_lo, DIM, KVDIM, KVDIM);

        // q = x @ wq (split, ~fp32)
        hipLaunchKernelGGL((mfma_gemm<true>), dim3(DIM / 128, SEQ / 128), t256, 0, stream,
                           x_hi, x_lo, wqT_hi, wqT_lo, qf, SEQ, DIM, DIM);
        // [k|v] = x @ [wk|wv] (split)
        hipLaunchKernelGGL((mfma_gemm<true>), dim3(2 * KVDIM / 128, SEQ / 128), t256, 0, stream,
                           x_hi, x_lo, kvT_hi, kvT_lo, kvf, SEQ, 2 * KVDIM, DIM);
        // wo transpose into freed wqT_hi region
        transpose_conv<<<dim3(DIM / 32, DIM / 32), t256, 0, stream>>>(wo, woT_hi, nullptr, DIM, DIM, 0);

        rope_kernel<<<(SEQ * NH * 64) / 256, t256, 0, stream>>>(qf, cosb, sinb, NH, NH * HD);
        rope_kernel<<<(SEQ * NKV * 64) / 256, t256, 0, stream>>>(kvf, cosb, sinb, NKV, 2 * KVDIM);
        blkmean_kernel<<<(NKV * NBLK * HD) / 256, t256, 0, stream>>>(kvf, kblk, 2 * KVDIM);

        attn_tile_kernel<<<dim3(NBLK, NH), t256, 0, stream>>>(qf, kvf, kvf + KVDIM, kblk, attn,
                                                              2 * KVDIM);

        // attn -> bf16, then out = attn @ wo (plain bf16)
        conv_hilo<<<SEQ * DIM / 4 / 256, t256, 0, stream>>>(attn, attnbf, nullptr);
        hipLaunchKernelGGL((mfma_gemm<false>), dim3(DIM / 128, SEQ / 128), t256, 0, stream,
                           attnbf, nullptr, woT_hi, nullptr, (float*)d_out, SEQ, DIM, DIM);
    } else {
        // ---- fallback: R3 fp32 pipeline (76 MB) ----
        float* qf   = (float*)ws;
        float* kf   = qf + (size_t)SEQ * DIM;
        float* vf   = kf + (size_t)SEQ * KVDIM;
        float* kblk = vf + (size_t)SEQ * KVDIM;
        float* attn = kblk + (size_t)NKV * NBLK * HD;

        gemm_kernel<<<dim3(DIM / 64, SEQ / 64), t256, 0, stream>>>(x, wq, qf, SEQ, DIM, DIM);
        gemm_kernel<<<dim3(KVDIM / 64, SEQ / 64), t256, 0, stream>>>(x, wk, kf, SEQ, KVDIM, DIM);
        gemm_kernel<<<dim3(KVDIM / 64, SEQ / 64), t256, 0, stream>>>(x, wv, vf, SEQ, KVDIM, DIM);
        rope_kernel<<<(SEQ * NH * 64) / 256, t256, 0, stream>>>(qf, cosb, sinb, NH, NH * HD);
        rope_kernel<<<(SEQ * NKV * 64) / 256, t256, 0, stream>>>(kf, cosb, sinb, NKV, KVDIM);
        blkmean_kernel<<<(NKV * NBLK * HD) / 256, t256, 0, stream>>>(kf, kblk, KVDIM);
        attn_tile_kernel<<<dim3(NBLK, NH), t256, 0, stream>>>(qf, kf, vf, kblk, attn, KVDIM);
        gemm_kernel<<<dim3(DIM / 64, SEQ / 64), t256, 0, stream>>>(attn, wo, (float*)d_out, SEQ, DIM, DIM);
    }
}